// Round 16
// baseline (144.047 us; speedup 1.0000x reference)
//
#include <hip/hip_runtime.h>

#define T_SEQ 50
#define BATCH 8192
#define INPUT 33
#define HID   256
#define BTILE 32
#define NTH   512

typedef __attribute__((ext_vector_type(8))) short short8;
typedef __attribute__((ext_vector_type(4))) short short4v;
typedef __attribute__((ext_vector_type(4))) float float4v;

// LDS (shorts): h dbuf + x dbuf = 43008 B. 1 block/CU, 8 waves.
#define H_STRIDE 264                       // 256 + 8 pad
#define X_STRIDE 72                        // 64 + 8 pad (cols: 0..32 x, 33 = 1.0, rest 0)
#define H0 0
#define H1 (BTILE * H_STRIDE)              // 8448
#define X0 (2 * BTILE * H_STRIDE)          // 16896
#define X1 (X0 + BTILE * X_STRIDE)         // 19200
#define LDS_SHORTS (X1 + BTILE * X_STRIDE) // 21504 shorts = 43008 B

__device__ __forceinline__ short f2bf(float v) {   // RNE f32 -> bf16 bits
  unsigned u = __builtin_bit_cast(unsigned, v);
  u = (u + 0x7FFFu + ((u >> 16) & 1u)) >> 16;
  return (short)u;
}

#define MFMA(a, b, c) __builtin_amdgcn_mfma_f32_16x16x32_bf16(a, b, c, 0, 0, 0)

// SWAPPED-OPERAND step (R10 layout) + NONTEMPORAL stores (R13 lever).
// C = W'·h^T: thread owns 4 consecutive j for one batch row =>
//   - outputs store DIRECT from registers (4 x nt dwordx4; no readback)
//   - h restage: 4 x ds_write_b64 (vs 16 scalar b16)
// In-place MFMA accumulation on hst (C-in = h; bc rides in win[.][1] k=33
// against the constant-1.0 x column). One lgkm-only barrier per step.
#define CSTEP(HR, XR, HW, XW, T)                                              \
  {                                                                           \
    float xp0 = 0.f, xp1 = 0.f, xp2 = 0.f;                                    \
    const bool more = (T) + 1 < T_SEQ;                                        \
    if (more) {                                                               \
      const float* xt1 = xpf + (size_t)((T) + 1) * xstep;                     \
      xp0 = xt1[e0]; xp1 = xt1[e1];                                           \
      if (p2) xp2 = xt1[e2];                                                  \
    }                                                                         \
    const short* hb = lds + (HR);                                             \
    const short* xb = lds + (XR);                                             \
    _Pragma("unroll") for (int ks = 0; ks < 8; ++ks) {                        \
      const int k = ks * 32 + kq * 8;                                         \
      short8 b0 = *(const short8*)(hb + colA * H_STRIDE + k);                 \
      short8 b1 = *(const short8*)(hb + (16 + colA) * H_STRIDE + k);          \
      hst[0][0] = MFMA(wf[0][ks], b0, hst[0][0]);                             \
      hst[0][1] = MFMA(wf[0][ks], b1, hst[0][1]);                             \
      hst[1][0] = MFMA(wf[1][ks], b0, hst[1][0]);                             \
      hst[1][1] = MFMA(wf[1][ks], b1, hst[1][1]);                             \
    }                                                                         \
    _Pragma("unroll") for (int kb = 0; kb < 2; ++kb) {                        \
      const int k = kb * 32 + kq * 8;                                         \
      short8 b0 = *(const short8*)(xb + colA * X_STRIDE + k);                 \
      short8 b1 = *(const short8*)(xb + (16 + colA) * X_STRIDE + k);          \
      hst[0][0] = MFMA(win[0][kb], b0, hst[0][0]);                            \
      hst[0][1] = MFMA(win[0][kb], b1, hst[0][1]);                            \
      hst[1][0] = MFMA(win[1][kb], b0, hst[1][0]);                            \
      hst[1][1] = MFMA(win[1][kb], b1, hst[1][1]);                            \
    }                                                                         \
    _Pragma("unroll") for (int jt = 0; jt < 2; ++jt)                          \
      _Pragma("unroll") for (int bt = 0; bt < 2; ++bt) {                      \
        float4v hv;                                                           \
        _Pragma("unroll") for (int i = 0; i < 4; ++i) {                       \
          float hn = fmaxf(0.5f * hst[jt][bt][i], 0.0f);                      \
          hst[jt][bt][i] = hn;                                                \
          hv[i] = hn;                                                         \
        }                                                                     \
        __builtin_nontemporal_store(                                          \
            hv, (float4v*)(outp + (size_t)(bt * 16) * HID + jt * 16));        \
        short4v hs;                                                           \
        hs[0] = f2bf(hv[0]); hs[1] = f2bf(hv[1]);                             \
        hs[2] = f2bf(hv[2]); hs[3] = f2bf(hv[3]);                             \
        *(short4v*)(lds + (HW) + (bt * 16 + colA) * H_STRIDE + c0 + jt * 16 + \
                    kq * 4) = hs;                                             \
      }                                                                       \
    if (more) {                                                               \
      lds[(XW) + r0 * X_STRIDE + c0x] = f2bf(xp0);                            \
      lds[(XW) + r1 * X_STRIDE + c1x] = f2bf(xp1);                            \
      if (p2) lds[(XW) + r2 * X_STRIDE + c2x] = f2bf(xp2);                    \
    }                                                                         \
    __builtin_amdgcn_sched_barrier(0);                                        \
    asm volatile("s_waitcnt lgkmcnt(0)" ::: "memory");                        \
    __builtin_amdgcn_s_barrier();                                             \
    __builtin_amdgcn_sched_barrier(0);                                        \
    outp += outstep;                                                          \
  }

__global__ __launch_bounds__(NTH, 2)
void ctrnn_kernel(const float* __restrict__ x, const int* __restrict__ sub_id,
                  const float* __restrict__ gates, const float* __restrict__ W_in,
                  const float* __restrict__ b_in, const float* __restrict__ W_h,
                  const float* __restrict__ b_h, float* __restrict__ out)
{
  __shared__ short lds[LDS_SHORTS];
  const int tid  = threadIdx.x;
  const int lane = tid & 63;
  const int wave = tid >> 6;
  const int colA = lane & 15;   // batch row within tile (B-frag col / C col)
  const int kq   = lane >> 4;   // k-chunk; C rows = j = kq*4+i
  const int c0   = wave * 32;   // wave's hidden-j base (8 waves x 32 j)
  const int brow0 = blockIdx.x * BTILE;

  const int sid = sub_id[0];
  const float* grow = gates + sid * HID;

  // ---- zero all LDS; then x col 33 = 1.0 (bf16 0x3F80) in BOTH x buffers ----
  {
    int* ldsi = (int*)lds;
    for (int i = tid; i < LDS_SHORTS / 2; i += NTH) ldsi[i] = 0;
  }
  __syncthreads();
  if (tid < 2 * BTILE) {
    int b = tid >> 5, r = tid & 31;
    lds[(b ? X1 : X0) + r * X_STRIDE + 33] = (short)0x3F80;
  }

  // ---- t-invariant operands in registers (the MFMA *A* operands) ----
  short8 wf[2][8];   // W_h' = diag(g)*W_h fragments: A[j=c0+jt*16+colA][k]
  short8 win[2][2];  // W_in fragments, k=33 slot carries bc
  #pragma unroll
  for (int jt = 0; jt < 2; ++jt) {
    const int col = c0 + jt * 16 + colA;
    const float g = grow[col];
    #pragma unroll
    for (int ks = 0; ks < 8; ++ks) {
      const float* wp = W_h + col * HID + ks * 32 + kq * 8;
      float4v w0 = *(const float4v*)wp;
      float4v w1 = *(const float4v*)(wp + 4);
      short8 f;
      f[0] = f2bf(g * w0[0]); f[1] = f2bf(g * w0[1]);
      f[2] = f2bf(g * w0[2]); f[3] = f2bf(g * w0[3]);
      f[4] = f2bf(g * w1[0]); f[5] = f2bf(g * w1[1]);
      f[6] = f2bf(g * w1[2]); f[7] = f2bf(g * w1[3]);
      wf[jt][ks] = f;
    }
    const float bcv = b_in[col] + g * b_h[col];
    #pragma unroll
    for (int kb = 0; kb < 2; ++kb) {
      short8 f;
      #pragma unroll
      for (int j = 0; j < 8; ++j) {
        const int kk = kb * 32 + kq * 8 + j;
        float v = (kk < INPUT) ? W_in[col * INPUT + kk]
                               : (kk == INPUT ? bcv : 0.0f);
        f[j] = f2bf(v);
      }
      win[jt][kb] = f;
    }
  }

  __syncthreads();   // zero + col-33 writes complete before x0 staging

  // ---- stage x_0 into buffer 0 ----
  {
    const float* xt = x + (size_t)brow0 * INPUT;
    for (int e = tid; e < BTILE * INPUT; e += NTH) {
      int r = e / INPUT, c = e - r * INPUT;
      lds[X0 + r * X_STRIDE + c] = f2bf(xt[e]);
    }
  }

  // x-prefetch invariants (1056 elems over 512 threads, 3 rounds)
  const int e0 = tid, e1 = tid + NTH, e2 = tid + 2 * NTH;
  const int r0 = e0 / INPUT, c0x = e0 - r0 * INPUT;
  const int r1 = e1 / INPUT, c1x = e1 - r1 * INPUT;
  const int r2 = e2 / INPUT, c2x = e2 - r2 * INPUT;
  const bool p2 = (e2 < BTILE * INPUT);

  // persistent f32 h at swapped C-layout: hst[jt][bt][i] =
  //   h[b = brow0 + bt*16 + colA][j = c0 + jt*16 + kq*4 + i]
  float4v hst[2][2];
  #pragma unroll
  for (int jt = 0; jt < 2; ++jt)
    #pragma unroll
    for (int bt = 0; bt < 2; ++bt)
      #pragma unroll
      for (int i = 0; i < 4; ++i) hst[jt][bt][i] = 0.0f;

  // store base: batch row = brow0 + bt*16 + colA, j base = c0 + jt*16 + kq*4
  float* outp = out + (size_t)(brow0 + colA) * HID + c0 + kq * 4;
  const int outstep = BATCH * HID;
  const float* xpf = x + (size_t)brow0 * INPUT;
  const int xstep = BATCH * INPUT;

  __syncthreads();   // x0 staged; h0 zeroed

  #pragma unroll 1
  for (int t2 = 0; t2 < T_SEQ / 2; ++t2) {
    CSTEP(H0, X0, H1, X1, 2 * t2);       // even: read buf0, write buf1
    CSTEP(H1, X1, H0, X0, 2 * t2 + 1);   // odd:  read buf1, write buf0
  }

  // h_last = h after step T-1 (in registers)
  {
    float* hp = out + (size_t)T_SEQ * BATCH * HID +
                (size_t)(brow0 + colA) * HID + c0 + kq * 4;
    #pragma unroll
    for (int jt = 0; jt < 2; ++jt)
      #pragma unroll
      for (int bt = 0; bt < 2; ++bt) {
        float4v hv;
        #pragma unroll
        for (int i = 0; i < 4; ++i) hv[i] = hst[jt][bt][i];
        __builtin_nontemporal_store(
            hv, (float4v*)(hp + (size_t)(bt * 16) * HID + jt * 16));
      }
  }
}

extern "C" void kernel_launch(void* const* d_in, const int* in_sizes, int n_in,
                              void* d_out, int out_size, void* d_ws, size_t ws_size,
                              hipStream_t stream) {
  const float* x    = (const float*)d_in[0];
  const int*   sid  = (const int*)  d_in[1];
  const float* gts  = (const float*)d_in[2];
  const float* W_in = (const float*)d_in[3];
  const float* b_in = (const float*)d_in[4];
  const float* W_h  = (const float*)d_in[5];
  const float* b_h  = (const float*)d_in[6];
  float* out = (float*)d_out;

  ctrnn_kernel<<<BATCH / BTILE, NTH, 0, stream>>>(x, sid, gts, W_in, b_in, W_h, b_h, out);
}

// Round 18
// 97.875 us; speedup vs baseline: 1.4717x; 1.4717x over previous
//
#include <hip/hip_runtime.h>

#define T_SEQ 50
#define BATCH 8192
#define INPUT 33
#define HID   256
#define BTILE 32
#define NTH   512

typedef __attribute__((ext_vector_type(8))) short short8;
typedef __attribute__((ext_vector_type(4))) short short4v;
typedef __attribute__((ext_vector_type(4))) float float4v;
typedef __attribute__((ext_vector_type(2))) int   int2v;

// bf16 h / x staging, double-buffered (units: shorts). 43 KB total.
#define H_STRIDE 264                       // 256 + 8 pad
#define X_STRIDE 72                        // 64 + 8
#define H0 0
#define H1 (BTILE * H_STRIDE)              // 8448
#define X0 (2 * BTILE * H_STRIDE)          // 16896
#define X1 (X0 + BTILE * X_STRIDE)         // 19200
#define LDS_SHORTS (X1 + BTILE * X_STRIDE) // 21504 shorts = 43008 B

__device__ __forceinline__ short f2bf(float v) {   // RNE f32 -> bf16 bits
  unsigned u = __builtin_bit_cast(unsigned, v);
  u = (u + 0x7FFFu + ((u >> 16) & 1u)) >> 16;
  return (short)u;
}
__device__ __forceinline__ float bf2f(short s) {
  return __builtin_bit_cast(float, ((unsigned)(unsigned short)s) << 16);
}

template <int CTRL>
__device__ __forceinline__ float dppf(float s) {   // DPP ctrl must be literal
  return __builtin_bit_cast(float,
      __builtin_amdgcn_mov_dpp(__builtin_bit_cast(int, s), CTRL, 0xF, 0xF, true));
}

// 4x4 transpose across a lane quad (p = lane&3). In: v[i] = B[i][p].
// Out: v[j] = B[p][j]. Pure VALU: 4 dpp quad_perm + cndmask selects.
__device__ __forceinline__ void quadtr(float4v& v, bool lo1, bool lo2) {
  float s, g;
  // stage 1 (xor 1): pairs (0,1), (2,3)
  s = lo1 ? v[1] : v[0];
  g = dppf<0xB1>(s);                 // quad_perm [1,0,3,2]
  v[0] = lo1 ? v[0] : g;
  v[1] = lo1 ? g : v[1];
  s = lo1 ? v[3] : v[2];
  g = dppf<0xB1>(s);
  v[2] = lo1 ? v[2] : g;
  v[3] = lo1 ? g : v[3];
  // stage 2 (xor 2): pairs (0,2), (1,3)
  s = lo2 ? v[2] : v[0];
  g = dppf<0x4E>(s);                 // quad_perm [2,3,0,1]
  v[0] = lo2 ? v[0] : g;
  v[2] = lo2 ? g : v[2];
  s = lo2 ? v[3] : v[1];
  g = dppf<0x4E>(s);
  v[1] = lo2 ? v[1] : g;
  v[3] = lo2 ? g : v[3];
}

// One step (R14 structure). ONLY change: h-restage uses DPP quad-transpose +
// cvt_pk + ds_write_b64 (32 LDS write-instrs/CU/step instead of 128 scalar
// b16). Outputs still read back post-barrier as full 1KB rows -> nt stores.
#define CSTEP(HR, XR, HW, XW, T)                                              \
  {                                                                           \
    float xp0 = 0.f, xp1 = 0.f, xp2 = 0.f;                                    \
    const bool more = (T) + 1 < T_SEQ;                                        \
    if (more) {                                                               \
      const float* xt1 = xpf + (size_t)((T) + 1) * xstep;                     \
      xp0 = xt1[e0]; xp1 = xt1[e1];                                           \
      if (p2) xp2 = xt1[e2];                                                  \
    }                                                                         \
    float4v acc[2][2];                                                        \
    _Pragma("unroll") for (int m = 0; m < 2; ++m)                             \
      _Pragma("unroll") for (int n = 0; n < 2; ++n)                           \
        _Pragma("unroll") for (int i = 0; i < 4; ++i)                         \
          acc[m][n][i] = hst[m][n][i] + bc[n];                                \
    const short* hb = lds + (HR);                                             \
    const short* xb = lds + (XR);                                             \
    _Pragma("unroll") for (int ks = 0; ks < 8; ++ks) {                        \
      const int k = ks * 32 + kq * 8;                                         \
      short8 a0 = *(const short8*)(hb + colA * H_STRIDE + k);                 \
      short8 a1 = *(const short8*)(hb + (16 + colA) * H_STRIDE + k);          \
      acc[0][0] = __builtin_amdgcn_mfma_f32_16x16x32_bf16(a0, wf[0][ks], acc[0][0], 0, 0, 0); \
      acc[0][1] = __builtin_amdgcn_mfma_f32_16x16x32_bf16(a0, wf[1][ks], acc[0][1], 0, 0, 0); \
      acc[1][0] = __builtin_amdgcn_mfma_f32_16x16x32_bf16(a1, wf[0][ks], acc[1][0], 0, 0, 0); \
      acc[1][1] = __builtin_amdgcn_mfma_f32_16x16x32_bf16(a1, wf[1][ks], acc[1][1], 0, 0, 0); \
    }                                                                         \
    _Pragma("unroll") for (int kb = 0; kb < 2; ++kb) {                        \
      const int k = kb * 32 + kq * 8;                                         \
      short8 a0 = *(const short8*)(xb + colA * X_STRIDE + k);                 \
      short8 a1 = *(const short8*)(xb + (16 + colA) * X_STRIDE + k);          \
      acc[0][0] = __builtin_amdgcn_mfma_f32_16x16x32_bf16(a0, win[0][kb], acc[0][0], 0, 0, 0); \
      acc[0][1] = __builtin_amdgcn_mfma_f32_16x16x32_bf16(a0, win[1][kb], acc[0][1], 0, 0, 0); \
      acc[1][0] = __builtin_amdgcn_mfma_f32_16x16x32_bf16(a1, win[0][kb], acc[1][0], 0, 0, 0); \
      acc[1][1] = __builtin_amdgcn_mfma_f32_16x16x32_bf16(a1, win[1][kb], acc[1][1], 0, 0, 0); \
    }                                                                         \
    _Pragma("unroll") for (int m = 0; m < 2; ++m)                             \
      _Pragma("unroll") for (int n = 0; n < 2; ++n) {                         \
        float4v tv;                                                           \
        _Pragma("unroll") for (int i = 0; i < 4; ++i) {                       \
          float hn = fmaxf(0.5f * acc[m][n][i], 0.0f);                        \
          hst[m][n][i] = hn;                                                  \
          tv[i] = hn;                                                         \
        }                                                                     \
        quadtr(tv, lo1, lo2);                                                 \
        int d0, d1;                                                           \
        asm("v_cvt_pk_bf16_f32 %0, %1, %2" : "=v"(d0) : "v"(tv[0]), "v"(tv[1])); \
        asm("v_cvt_pk_bf16_f32 %0, %1, %2" : "=v"(d1) : "v"(tv[2]), "v"(tv[3])); \
        int2v dd; dd[0] = d0; dd[1] = d1;                                     \
        *(int2v*)(lds + (HW) + (m * 16 + kq * 4 + pq) * H_STRIDE +            \
                  c0 + n * 16 + 4 * qq) = dd;                                 \
      }                                                                       \
    if (more) {                                                               \
      lds[(XW) + r0 * X_STRIDE + c0x] = f2bf(xp0);                            \
      lds[(XW) + r1 * X_STRIDE + c1x] = f2bf(xp1);                            \
      if (p2) lds[(XW) + r2 * X_STRIDE + c2x] = f2bf(xp2);                    \
    }                                                                         \
    __builtin_amdgcn_sched_barrier(0);                                        \
    asm volatile("s_waitcnt lgkmcnt(0)" ::: "memory");                        \
    __builtin_amdgcn_s_barrier();                                             \
    __builtin_amdgcn_sched_barrier(0);                                        \
    _Pragma("unroll") for (int j = 0; j < 4; ++j) {                           \
      short4v hv = *(const short4v*)(lds + (HW) + (4 * wave + j) * H_STRIDE + 4 * lane); \
      float4v ov;                                                             \
      ov[0] = bf2f(hv[0]); ov[1] = bf2f(hv[1]);                               \
      ov[2] = bf2f(hv[2]); ov[3] = bf2f(hv[3]);                               \
      __builtin_nontemporal_store(ov, (float4v*)(outg + j * HID));            \
    }                                                                         \
    outg += outstep;                                                          \
  }

__global__ __launch_bounds__(NTH, 2)
void ctrnn_kernel(const float* __restrict__ x, const int* __restrict__ sub_id,
                  const float* __restrict__ gates, const float* __restrict__ W_in,
                  const float* __restrict__ b_in, const float* __restrict__ W_h,
                  const float* __restrict__ b_h, float* __restrict__ out)
{
  __shared__ short lds[LDS_SHORTS];
  const int tid  = threadIdx.x;
  const int lane = tid & 63;
  const int wave = tid >> 6;
  const int colA = lane & 15;   // A-row (batch) / C-col within tile
  const int kq   = lane >> 4;   // k-quadrant / C-row group
  const int c0   = wave * 32;   // wave's output-column base (8 waves x 32)
  const int pq   = colA & 3;    // quad position (transpose row select)
  const int qq   = colA >> 2;   // quad index (column-quad select)
  const bool lo1 = (colA & 1) == 0;
  const bool lo2 = (colA & 2) == 0;
  const int brow0 = blockIdx.x * BTILE;

  const int sid = sub_id[0];
  const float* grow = gates + sid * HID;

  // ---- zero h/x staging (h0 = 0; x pad columns stay 0 forever) ----
  {
    int* ldsi = (int*)lds;
    #pragma unroll 4
    for (int i = tid; i < LDS_SHORTS / 2; i += NTH) ldsi[i] = 0;
  }

  // ---- t-invariant operands in REGISTERS ----
  short8 wf[2][8];   // B-fragments of W_h' = diag(g)*W_h  (64 VGPRs)
  short8 win[2][2];  // B-fragments of W_in (zero-padded K=64)
  float  bc[2];
  #pragma unroll
  for (int n = 0; n < 2; ++n) {
    const int col = c0 + n * 16 + colA;
    const float g = grow[col];
    #pragma unroll
    for (int ks = 0; ks < 8; ++ks) {
      const float* wp = W_h + col * HID + ks * 32 + kq * 8;
      float4v w0 = *(const float4v*)wp;
      float4v w1 = *(const float4v*)(wp + 4);
      short8 f;
      f[0] = f2bf(g * w0[0]); f[1] = f2bf(g * w0[1]);
      f[2] = f2bf(g * w0[2]); f[3] = f2bf(g * w0[3]);
      f[4] = f2bf(g * w1[0]); f[5] = f2bf(g * w1[1]);
      f[6] = f2bf(g * w1[2]); f[7] = f2bf(g * w1[3]);
      wf[n][ks] = f;
    }
    #pragma unroll
    for (int kb = 0; kb < 2; ++kb) {
      short8 f;
      #pragma unroll
      for (int j = 0; j < 8; ++j) {
        int kk = kb * 32 + kq * 8 + j;
        f[j] = (kk < INPUT) ? f2bf(W_in[col * INPUT + kk]) : (short)0;
      }
      win[n][kb] = f;
    }
    bc[n] = b_in[col] + g * b_h[col];
  }

  __syncthreads();   // zero-fill complete before x0 staging

  // ---- stage x_0 into buffer 0 ----
  {
    const float* xt = x + (size_t)brow0 * INPUT;
    for (int e = tid; e < BTILE * INPUT; e += NTH) {
      int r = e / INPUT, c = e - r * INPUT;
      lds[X0 + r * X_STRIDE + c] = f2bf(xt[e]);
    }
  }

  // x-prefetch invariants (threads cover elems tid, tid+512, tid+1024 of 1056)
  const int e0 = tid, e1 = tid + NTH, e2 = tid + 2 * NTH;
  const int r0 = e0 / INPUT, c0x = e0 - r0 * INPUT;
  const int r1 = e1 / INPUT, c1x = e1 - r1 * INPUT;
  const int r2 = e2 / INPUT, c2x = e2 - r2 * INPUT;
  const bool p2 = (e2 < BTILE * INPUT);

  // persistent f32 h master at MFMA C-layout
  float4v hst[2][2];
  #pragma unroll
  for (int m = 0; m < 2; ++m)
    #pragma unroll
    for (int n = 0; n < 2; ++n)
      #pragma unroll
      for (int i = 0; i < 4; ++i) hst[m][n][i] = 0.0f;

  // coalesced store base: wave w owns tile rows 4w..4w+3, lane covers 16B
  float* outg = out + (size_t)(brow0 + 4 * wave) * HID + 4 * lane;
  const int outstep = BATCH * HID;
  const float* xpf = x + (size_t)brow0 * INPUT;
  const int xstep = BATCH * INPUT;

  __syncthreads();   // x0 staged; h0 zeroed

  #pragma unroll 1
  for (int t2 = 0; t2 < T_SEQ / 2; ++t2) {
    CSTEP(H0, X0, H1, X1, 2 * t2);       // even: read buf0, write buf1
    CSTEP(H1, X1, H0, X0, 2 * t2 + 1);   // odd:  read buf1, write buf0
  }

  // h_last == output[T-1]; read back from H0 (written by step T-1)
  {
    float* hl = out + (size_t)T_SEQ * BATCH * HID +
                (size_t)(brow0 + 4 * wave) * HID + 4 * lane;
    #pragma unroll
    for (int j = 0; j < 4; ++j) {
      short4v hv = *(const short4v*)(lds + H0 + (4 * wave + j) * H_STRIDE + 4 * lane);
      float4v ov;
      ov[0] = bf2f(hv[0]); ov[1] = bf2f(hv[1]);
      ov[2] = bf2f(hv[2]); ov[3] = bf2f(hv[3]);
      __builtin_nontemporal_store(ov, (float4v*)(hl + j * HID));
    }
  }
}

extern "C" void kernel_launch(void* const* d_in, const int* in_sizes, int n_in,
                              void* d_out, int out_size, void* d_ws, size_t ws_size,
                              hipStream_t stream) {
  const float* x    = (const float*)d_in[0];
  const int*   sid  = (const int*)  d_in[1];
  const float* gts  = (const float*)d_in[2];
  const float* W_in = (const float*)d_in[3];
  const float* b_in = (const float*)d_in[4];
  const float* W_h  = (const float*)d_in[5];
  const float* b_h  = (const float*)d_in[6];
  float* out = (float*)d_out;

  ctrnn_kernel<<<BATCH / BTILE, NTH, 0, stream>>>(x, sid, gts, W_in, b_in, W_h, b_h, out);
}